// Round 16
// baseline (207.803 us; speedup 1.0000x reference)
//
#include <hip/hip_runtime.h>

typedef short bf16x8 __attribute__((ext_vector_type(8)));
typedef float f32x4  __attribute__((ext_vector_type(4)));

__device__ __forceinline__ unsigned short f2bf(float f) {
    unsigned int u = __float_as_uint(f);
    u += 0x7FFFu + ((u >> 16) & 1u);
    return (unsigned short)(u >> 16);
}

// tanh-form GELU: x * sigmoid(2*0.79788456*(x + 0.044715 x^3)). |err| <~5e-4 abs.
__device__ __forceinline__ float gelu_f(float x) {
    float x2 = x * x;
    float u = x * (-1.5957691216f - 0.0713548162f * x2);
    float e = __expf(u);
    return x * __builtin_amdgcn_rcpf(1.0f + e);
}

// ---------- fused prep: x cvt + w1 cvt + w2 transpose (one launch) ----------
__global__ void prep_all(const float* __restrict__ x,
                         const float* __restrict__ w1,
                         const float* __restrict__ w2,
                         unsigned short* __restrict__ xb,
                         unsigned short* __restrict__ w1b,
                         unsigned short* __restrict__ w2t) {
    __shared__ float tile[32][33];
    const int b = blockIdx.x, t = threadIdx.x;
    const int tx = t & 31, ty = t >> 5;                   // 32 x 8
    const int o0 = (b % 24) * 32, h0 = (b / 24) * 32;
    #pragma unroll
    for (int r = 0; r < 32; r += 8)
        tile[ty + r][tx] = w2[(size_t)(h0 + ty + r) * 768 + o0 + tx];
    __syncthreads();
    #pragma unroll
    for (int r = 0; r < 32; r += 8) {
        int o = ty + r;
        w2t[(size_t)(o0 + o) * 3072 + h0 + tx] = f2bf(tile[tx][o]);
    }
    constexpr int NX = 16384 * 768 / 4, NW = 3072 * 768 / 4;
    const int stride = gridDim.x * 256;
    for (int i = b * 256 + t; i < NX + NW; i += stride) {
        const float4 v = (i < NX) ? ((const float4*)x)[i] : ((const float4*)w1)[i - NX];
        ushort4 r;
        r.x = f2bf(v.x); r.y = f2bf(v.y); r.z = f2bf(v.z); r.w = f2bf(v.w);
        if (i < NX) ((ushort4*)xb)[i] = r; else ((ushort4*)w1b)[i - NX] = r;
    }
}

// ====== gemm_rp: 256xBN, BK=64, REGISTER-double-buffered pipeline ==========
// Breaks the read->MFMA same-phase dependency that pinned 7 schedule variants
// at 37% MfmaUtil. Two fragment sets S0/S1. Per K-tile kt (LDS buf c = kt&1):
//  A: read S1 <- kh1(kt)[buf c]   || MFMA(S0 = kh0(kt))      (independent)
//  B: lgkm(0); s_barrier           => all reads of buf c globally complete
//  C: STAGE tile kt+2 -> buf c (8 loads, WAR-safe per B);
//     vmcnt(8)+s_barrier           => certifies buf c' (stage kt+1 retired;
//                                     this tile's 8 stay in flight, never 0);
//     read S0 <- kh0(kt+1)[buf c'] || MFMA(S1 = kh1(kt))     (independent)
// Final tile peeled (no stage/gate).
// R15 fix (R14 absmax 86016): RDB takes the A-REGION base and adds boffb
// (+32768) internally. R14's phase-A call RDB(c+49152) hit c+81920 (wrong
// buffer for c=0; LDS OOB 147456 > 131072 for c=65536). Correct arg for
// B-kh1 is the A-kh1 base: RDB(c+16384). Same fix in the peeled tail.
// Ledger (re-verified): prologue 16 outstanding -> GATE retires tile0;
// every in-loop GATE sees 16 -> retires 8; tile NT-1 staged by iter NT-3
// into buf (NT-1)&1; clamped restages hit only dead regions.
// Regions: buf c at c: {A-kh0:+0, A-kh1:+16384, B-kh0:+32768, B-kh1:+49152}.
// B always staged as 256 rows (BN=192: rows 192..255 staged-never-read;
// global reads stay inside d_ws). Swizzle (R7-verified, 0 conflicts): 64B
// rows, phys16Bslot = lg ^ ((row>>1)&3); inverse on global src, fwd on read.
template <int EPI, int K, int N, int BN>
__global__ __launch_bounds__(512, 2) void gemm_rp(
    const unsigned short* __restrict__ A,
    const unsigned short* __restrict__ B,
    const float* __restrict__ bias,
    void* __restrict__ Cp) {
    constexpr int NREP = BN / 64;
    __shared__ __align__(16) char lds[131072];
    const int t = threadIdx.x;
    const int w = t >> 6, l = t & 63;
    constexpr int ntiles = N / BN;

    int bid = blockIdx.x, nwg = gridDim.x;
    int wgid = ((nwg & 7) == 0) ? ((bid & 7) * (nwg >> 3) + (bid >> 3)) : bid;
    const int mt = wgid / ntiles, nt = wgid % ntiles;
    const int m0 = mt << 8, n0 = nt * BN;
    const int wr = w >> 2, wc = w & 3;

    // staging: unit u covers prow=u>>2 (0..255), phys slot u&3; logical slot
    // lg = (u&3) ^ ((prow>>1)&3) = (u&3) ^ ((u>>3)&3); global = prow*K + lg*8.
    const int u1 = t + 512;
    const int gu0 = (t >> 2) * K + (((t & 3) ^ ((t >> 3) & 3)) << 3);
    const int gu1 = (u1 >> 2) * K + (((u1 & 3) ^ ((u1 >> 3) & 3)) << 3);
    const unsigned short* Abase = A + (size_t)m0 * K;
    const unsigned short* Bbase = B + (size_t)n0 * K;

#define STAGE(PTR, KT, KS, REG) { \
    const unsigned short* g_ = (PTR) + (KT) * 64 + (KS) * 32; \
    __builtin_amdgcn_global_load_lds( \
        (const __attribute__((address_space(1))) void*)(g_ + gu0), \
        (__attribute__((address_space(3))) void*)(lds + (REG) + t * 16), 16, 0, 0); \
    __builtin_amdgcn_global_load_lds( \
        (const __attribute__((address_space(1))) void*)(g_ + gu1), \
        (__attribute__((address_space(3))) void*)(lds + (REG) + 8192 + t * 16), 16, 0, 0); }
#define PIN() { asm volatile("" ::: "memory"); }
#define GATE() { asm volatile("s_waitcnt vmcnt(8)\n\ts_barrier" ::: "memory"); }
#define LGKMB() { asm volatile("s_waitcnt lgkmcnt(0)\n\ts_barrier" ::: "memory"); }
#define RDB(RG, BV) { const char* p_ = lds + (RG) + boffb; \
    _Pragma("unroll") \
    for (int ni_ = 0; ni_ < NREP; ++ni_) BV[ni_] = *(const bf16x8*)(p_ + ni_ * 1024); }
#define RDA(RG, MH, DST) { const char* p_ = lds + (RG) + aoffb + (MH) * 4096; \
    DST[0] = *(const bf16x8*)(p_);        DST[1] = *(const bf16x8*)(p_ + 1024); \
    DST[2] = *(const bf16x8*)(p_ + 2048); DST[3] = *(const bf16x8*)(p_ + 3072); }
#define MFMAQ(MB, AV, BV) \
    __builtin_amdgcn_s_setprio(1); \
    _Pragma("unroll") \
    for (int mi = 0; mi < 4; ++mi) { \
        _Pragma("unroll") \
        for (int ni = 0; ni < NREP; ++ni) \
            acc[MB * 4 + mi][ni] = __builtin_amdgcn_mfma_f32_16x16x32_bf16( \
                AV[mi], BV[ni], acc[MB * 4 + mi][ni], 0, 0, 0); \
    } \
    __builtin_amdgcn_s_setprio(0);

    // ds_read: A frag row = wr*128 + mh*64 + mi*16 + lr, slot cR = l>>4,
    // phys = cR ^ ((row>>1)&3) = cR ^ ((lr>>1)&3). B frag row = wc*(BN/4)+ni*16+lr.
    const int cR = l >> 4, lr = l & 15;
    const int swz = (cR ^ ((lr >> 1) & 3)) << 4;
    const int aoffb = (wr * 128 + lr) * 64 + swz;              // + mh*4096 + mi*1024
    const int boffb = 32768 + (wc * (BN / 4) + lr) * 64 + swz; // + ni*1024

    f32x4 acc[8][NREP];
    {
        f32x4 z = {0.f, 0.f, 0.f, 0.f};
        #pragma unroll
        for (int i = 0; i < 8; ++i)
            #pragma unroll
            for (int j = 0; j < NREP; ++j) acc[i][j] = z;
    }
    bf16x8 av0[4], avh0[4], bv0[NREP];     // S0: kh0 fragments
    bf16x8 av1[4], avh1[4], bv1[NREP];     // S1: kh1 fragments

    constexpr int NT = K >> 6;             // K-tiles of 64

    // Prologue: stage tile0 -> buf0, tile1 -> buf1 (issue order = ledger order).
    STAGE(Abase, 0, 0, 0);      STAGE(Bbase, 0, 0, 32768);   PIN();
    STAGE(Abase, 0, 1, 16384);  STAGE(Bbase, 0, 1, 49152);   PIN();
    STAGE(Abase, 1, 0, 65536);  STAGE(Bbase, 1, 0, 98304);   PIN();
    STAGE(Abase, 1, 1, 81920);  STAGE(Bbase, 1, 1, 114688);  PIN();
    GATE();                                 // certify buf0 (tile0); 8 in flight
    RDB(0, bv0); RDA(0, 0, av0); RDA(0, 1, avh0);   // S0 <- kh0(tile0)

    for (int kt = 0; kt < NT - 1; ++kt) {
        const int c  = (kt & 1) << 16;      // this tile's buffer byte offset
        const int cp = 65536 - c;           // other buffer
        const int k2 = (kt + 2 < NT) ? kt + 2 : NT - 1;
        // A: read S1 <- kh1(kt) [buf c]  ||  MFMA(S0)
        RDB(c + 16384, bv1);                           // B-kh1 (A-kh1 base arg)
        RDA(c + 16384, 0, av1); RDA(c + 16384, 1, avh1);
        MFMAQ(0, av0, bv0); MFMAQ(1, avh0, bv0);
        // B: all reads of buf c globally complete
        LGKMB();
        // C: restage buf c with tile kt+2; certify buf c'; read S0; MFMA(S1)
        STAGE(Abase, k2, 0, c);          STAGE(Bbase, k2, 0, c + 32768);  PIN();
        STAGE(Abase, k2, 1, c + 16384);  STAGE(Bbase, k2, 1, c + 49152);  PIN();
        GATE();
        RDB(cp, bv0); RDA(cp, 0, av0); RDA(cp, 1, avh0);   // S0 <- kh0(kt+1)
        MFMAQ(0, av1, bv1); MFMAQ(1, avh1, bv1);
    }
    // Final tile NT-1 (peeled: no stage, no gate)
    {
        const int c = ((NT - 1) & 1) << 16;
        RDB(c + 16384, bv1);                           // B-kh1 (A-kh1 base arg)
        RDA(c + 16384, 0, av1); RDA(c + 16384, 1, avh1);
        MFMAQ(0, av0, bv0); MFMAQ(1, avh0, bv0);
        asm volatile("s_waitcnt lgkmcnt(0)" ::: "memory");
        MFMAQ(0, av1, bv1); MFMAQ(1, avh1, bv1);
    }
    asm volatile("s_waitcnt vmcnt(0)" ::: "memory");
#undef STAGE
#undef PIN
#undef GATE
#undef LGKMB
#undef RDB
#undef RDA
#undef MFMAQ

    // Epilogue. C/D frag: col = lane&15, row = (lane>>4)*4 + j  (m89-verified)
    const int colb = n0 + wc * (BN / 4) + lr;
    if constexpr (EPI == 0) {
        unsigned short* Cb = (unsigned short*)Cp;
        float bvs[NREP];
        #pragma unroll
        for (int ni = 0; ni < NREP; ++ni) bvs[ni] = bias[colb + ni * 16];
        #pragma unroll
        for (int mi = 0; mi < 8; ++mi)
            #pragma unroll
            for (int j = 0; j < 4; ++j) {
                size_t row = m0 + wr * 128 + mi * 16 + cR * 4 + j;
                #pragma unroll
                for (int ni = 0; ni < NREP; ++ni) {
                    float v = acc[mi][ni][j] + bvs[ni];
                    Cb[row * N + colb + ni * 16] = f2bf(gelu_f(v));
                }
            }
    } else {
        float* Cf = (float*)Cp;
        #pragma unroll
        for (int mi = 0; mi < 8; ++mi)
            #pragma unroll
            for (int j = 0; j < 4; ++j) {
                size_t row = m0 + wr * 128 + mi * 16 + cR * 4 + j;
                #pragma unroll
                for (int ni = 0; ni < NREP; ++ni)
                    Cf[row * N + colb + ni * 16] = acc[mi][ni][j];
            }
    }
}

extern "C" void kernel_launch(void* const* d_in, const int* in_sizes, int n_in,
                              void* d_out, int out_size, void* d_ws, size_t ws_size,
                              hipStream_t stream) {
    const float* x  = (const float*)d_in[0];   // [T, 768]
    const float* w1 = (const float*)d_in[1];   // [3072, 768]
    const float* b1 = (const float*)d_in[2];   // [3072]
    const float* w2 = (const float*)d_in[3];   // [3072, 768]
    float* out = (float*)d_out;                // [T, 768] fp32

    const int T = 16384, DIN = 768, DH = 3072, DOUT = 768;

    unsigned short* xb  = (unsigned short*)d_ws;            // T*DIN bf16
    unsigned short* w1b = xb  + (size_t)T * DIN;            // DH*DIN bf16 ([N][K])
    unsigned short* w2t = w1b + (size_t)DH * DIN;           // DOUT*DH bf16 ([N][K])
    unsigned short* h   = w2t + (size_t)DOUT * DH;          // CH*DH bf16
    // NOTE: gemm_rp<...,192> stages 256 B-rows; last n-tile reads 64 rows
    // past w2t into h — allocated, never consumed.

    size_t fixed = ((size_t)T * DIN + (size_t)DH * DIN + (size_t)DOUT * DH) * 2;
    int CH = T;
    while (CH > 256 && fixed + (size_t)CH * DH * 2 > ws_size) CH >>= 1;

    prep_all<<<2304, 256, 0, stream>>>(x, w1, w2, xb, w1b, w2t);

    for (int c0 = 0; c0 < T; c0 += CH) {
        // h = GELU(x_chunk * W1^T + b)      M=CH, N=DH=3072, K=DIN=768, BN=256
        gemm_rp<0, 768, 3072, 256><<<(CH / 256) * (DH / 256), 512, 0, stream>>>(
            xb + (size_t)c0 * DIN, w1b, b1, h);
        // out_chunk = h * W2T^T             M=CH, N=DOUT=768, K=DH=3072, BN=192
        gemm_rp<1, 3072, 768, 192><<<(CH / 256) * (DOUT / 192), 512, 0, stream>>>(
            h, w2t, b1, out + (size_t)c0 * DOUT);
    }
}